// Round 17
// baseline (49.975 us; speedup 1.0000x reference)
//
#include <hip/hip_runtime.h>

#define NDOCS 64
#define NPASS 1024
#define TITLE_LEN 128
#define SEQ 256
#define NEDGES 32768
#define NNODES 2112   // NDOCS + 2*NPASS
#define DIM 768
#define SPAN_TOK 30522
#define NREL 2
#define NBINS (NREL * NNODES)   // 4224
#define SPAN0 (NNODES - NPASS)  // 1088
#define CAP 48                  // max in-edges per bin; P(overflow)~1e-26
#define NBLK 512                // 512 blocks x 4 waves = 2048 waves; 2/CU resident
#define BAR_STRIDE 256          // ints per barrier slot (3 slots)
#define CLRINTS (NBINS + 3 * BAR_STRIDE)

__device__ inline float wred(float s) {
#pragma unroll
  for (int off = 32; off > 0; off >>= 1) s += __shfl_down(s, off);
  return s;
}
__device__ inline float dot4(float4 a, float4 b) {
  return a.x * b.x + a.y * b.y + a.z * b.z + a.w * b.w;
}
// coherent (agent-scope relaxed) accessors: bypass non-coherent L1/L2
__device__ inline float cload(const float* p) {
  return __hip_atomic_load(p, __ATOMIC_RELAXED, __HIP_MEMORY_SCOPE_AGENT);
}
__device__ inline void cstore(float* p, float x) {
  __hip_atomic_store(p, x, __ATOMIC_RELAXED, __HIP_MEMORY_SCOPE_AGENT);
}
__device__ inline int ciload(const int* p) {
  return __hip_atomic_load(p, __ATOMIC_RELAXED, __HIP_MEMORY_SCOPE_AGENT);
}
__device__ inline void cistore(int* p, int x) {
  __hip_atomic_store(p, x, __ATOMIC_RELAXED, __HIP_MEMORY_SCOPE_AGENT);
}

// fully-relaxed grid barrier: no cache-maintenance ops. Store completion is
// guaranteed by __syncthreads()'s vmcnt(0) drain; data correctness by all
// cross-stage traffic using coherent accessors. Two-level arrival tree
// (8 group counters on separate lines -> root -> flag) avoids same-line
// atomic serialization across 512 blocks.
__device__ inline void gbar(int* bars, int i) {
  __syncthreads();  // drains each thread's vmcnt -> stores at coherence point
  if (threadIdx.x == 0) {
    int* base = bars + i * BAR_STRIDE;
    int g = blockIdx.x >> 6;  // 8 groups of 64 blocks
    if (__hip_atomic_fetch_add(base + g * 16, 1, __ATOMIC_RELAXED,
                               __HIP_MEMORY_SCOPE_AGENT) == 63) {
      if (__hip_atomic_fetch_add(base + 128, 1, __ATOMIC_RELAXED,
                                 __HIP_MEMORY_SCOPE_AGENT) == 7) {
        __hip_atomic_store(base + 144, 1, __ATOMIC_RELAXED,
                           __HIP_MEMORY_SCOPE_AGENT);
      }
    }
    while (__hip_atomic_load(base + 144, __ATOMIC_RELAXED,
                             __HIP_MEMORY_SCOPE_AGENT) == 0)
      __builtin_amdgcn_s_sleep(1);
  }
  __syncthreads();
}

__global__ __launch_bounds__(256) void init_kernel(int* __restrict__ clr) {
  int i = blockIdx.x * 256 + threadIdx.x;
  if (i < CLRINTS) clr[i] = 0;
}

__global__ __launch_bounds__(256, 2) void mega_kernel(
    const int* __restrict__ doc_ids, const int* __restrict__ pass_ids,
    const int* __restrict__ src, const int* __restrict__ dst,
    const int* __restrict__ et, const float* __restrict__ embed,
    const float* __restrict__ w_root1, const float* __restrict__ w_rel1,
    const float* __restrict__ b1, const float* __restrict__ w_root2,
    const float* __restrict__ w_rel2, const float* __restrict__ b2,
    const float* __restrict__ clf_w, const float* __restrict__ clf_b,
    float* __restrict__ uf /* (3*DIM+1)*4 */, float* __restrict__ Tqf /* NNODES*16 */,
    float* __restrict__ v /* 3*DIM+1 */, int* __restrict__ deg,
    int* __restrict__ bars, int* __restrict__ bucket, float* __restrict__ out) {
  __shared__ __align__(16) float lds[(3 * DIM + 1) * 4];
  __shared__ float red[2][2];
  const int tid = threadIdx.x;
  const int w = blockIdx.x * 4 + (tid >> 6);  // global wave 0..2047
  const int lane = tid & 63;
  const int gtid = blockIdx.x * 256 + tid;

  // ======== stage A: foldv (v = Wcat2 . clf_w) || bucket-scatter ========
  for (int k = w; k <= 3 * DIM; k += 4 * NBLK) {
    const float* row = (k < DIM) ? w_root2 + (size_t)k * DIM
                     : (k < 3 * DIM) ? w_rel2 + (size_t)(k - DIM) * DIM
                                     : b2;
    const float4* r4 = (const float4*)row;
    const float4* w4 = (const float4*)clf_w;
    float s = dot4(r4[lane], w4[lane]) + dot4(r4[lane + 64], w4[lane + 64]) +
              dot4(r4[lane + 128], w4[lane + 128]);
    s = wred(s);
    if (lane == 0) cstore(&v[k], s + (k == 3 * DIM ? clf_b[0] : 0.f));
  }
  if (gtid < NEDGES) {
    int bin = et[gtid] * NNODES + dst[gtid];
    int slot = atomicAdd(&deg[bin], 1);  // device-scope: coherent
    if (slot < CAP) cistore(&bucket[bin * CAP + slot], src[gtid]);
  }
  gbar(bars, 0);

  // ======== stage B: foldu (U[k][j] = row_k(Wcat1) . v_j) ========
  for (int i = tid; i <= 3 * DIM; i += 256) lds[i] = cload(&v[i]);
  __syncthreads();
  for (int k = w; k <= 3 * DIM; k += 4 * NBLK) {
    const float* row = (k < DIM) ? w_root1 + (size_t)k * DIM
                     : (k < 3 * DIM) ? w_rel1 + (size_t)(k - DIM) * DIM
                                     : b1;
    const float4* r4 = (const float4*)row;
    const float4* v0 = (const float4*)lds;
    const float4* v1 = (const float4*)(lds + DIM);
    const float4* v2 = (const float4*)(lds + 2 * DIM);
    float s0 = 0.f, s1 = 0.f, s2 = 0.f;
#pragma unroll
    for (int i = 0; i < 3; ++i) {
      int j = lane + i * 64;
      float4 r = r4[j];
      s0 += dot4(r, v0[j]);
      s1 += dot4(r, v1[j]);
      s2 += dot4(r, v2[j]);
    }
    s0 = wred(s0); s1 = wred(s1); s2 = wred(s2);
    if (lane == 0) {
      cstore(&uf[k * 4 + 0], s0);
      cstore(&uf[k * 4 + 1], s1);
      cstore(&uf[k * 4 + 2], s2);
    }
  }
  gbar(bars, 1);

  // ======== stage C: T[m][a][j] = x0[m] . U_a[:,j]  (1 node per wave) ========
  for (int i = tid; i < (3 * DIM + 1) * 4; i += 256) lds[i] = cload(&uf[i]);
  __syncthreads();
  for (int m = w; m < NNODES; m += 4 * NBLK) {
    int tok = (m < NDOCS) ? doc_ids[m * TITLE_LEN]
            : (m < NDOCS + NPASS) ? pass_ids[(m - NDOCS) * SEQ]
                                  : SPAN_TOK;
    const float4* e4 = (const float4*)(embed + (size_t)tok * DIM);
    float s[9] = {};
#pragma unroll
    for (int i = 0; i < 3; ++i) {
      int j = lane + i * 64;
      float4 ev = e4[j];
#pragma unroll
      for (int q = 0; q < 4; ++q) {
        int k = j * 4 + q;
        float e1 = (q == 0) ? ev.x : (q == 1) ? ev.y : (q == 2) ? ev.z : ev.w;
#pragma unroll
        for (int a = 0; a < 3; ++a) {
          int base = (a * DIM + k) * 4;
          s[a * 3 + 0] += e1 * lds[base + 0];
          s[a * 3 + 1] += e1 * lds[base + 1];
          s[a * 3 + 2] += e1 * lds[base + 2];
        }
      }
    }
#pragma unroll
    for (int a = 0; a < 9; ++a) s[a] = wred(s[a]);
    if (lane == 0) {
#pragma unroll
      for (int a = 0; a < 3; ++a)
#pragma unroll
        for (int j = 0; j < 3; ++j)
          cstore(&Tqf[m * 16 + a * 4 + j], s[a * 3 + j]);
    }
  }
  gbar(bars, 2);

  // ======== stage D: final. 2 waves per span node ========
  {
    int p = tid >> 7;            // pair 0/1 within block
    int tt = tid & 127;
    int lwv = tt >> 6;
    int i = blockIdx.x * 2 + p;  // span idx 0..1023 (NBLK*2 == NPASS)
    int n = SPAN0 + i;
    float Dj[3];
#pragma unroll
    for (int j = 0; j < 3; ++j) Dj[j] = cload(&uf[3 * DIM * 4 + j]);
    int c0n = ciload(&deg[n]), c1n = ciload(&deg[NNODES + n]);
    float i0n = 1.f / fmaxf((float)c0n, 1.f);
    float i1n = 1.f / fmaxf((float)c1n, 1.f);
    int tot = c0n + c1n;
    int q = tt & 3;
    float zpart = 0.f;
    for (int o = tt >> 2; o < tot; o += 32) {
      int r = (o < c0n) ? 0 : 1;
      int oo = (o < c0n) ? o : o - c0n;
      int s = ciload(&bucket[(r * NNODES + n) * CAP + oo]);
      int j = 1 + r;
      float contrib = 0.f;
      if (q == 0)
        contrib = cload(&Tqf[s * 16 + j * 4 + 0])  // T[s][1+r][0]
                + cload(&Tqf[s * 16 + j])          // T[s][0][1+r]
                + Dj[j];
#pragma unroll
      for (int rp = 0; rp < 2; ++rp) {
        int cs = ciload(&deg[rp * NNODES + s]);
        float ssum = 0.f;
        for (int e = q; e < cs; e += 4) {
          int sp = ciload(&bucket[(rp * NNODES + s) * CAP + e]);
          ssum += cload(&Tqf[sp * 16 + (1 + rp) * 4 + j]);
        }
        contrib += ssum / fmaxf((float)cs, 1.f);
      }
      zpart += ((r == 0) ? i0n : i1n) * contrib;
    }
    zpart = wred(zpart);
    if ((tt & 63) == 0) red[p][lwv] = zpart;
    __syncthreads();
    if (tt == 0) {
      float z = cload(&Tqf[n * 16 + 0]) + Dj[0] + cload(&v[3 * DIM]) +
                red[p][0] + red[p][1];
      float sc = 1.f / (1.f + expf(-z));
      out[i] = expf(sc * 5.f);  // exp(score / TAU), TAU = 0.2
    }
  }
}

extern "C" void kernel_launch(void* const* d_in, const int* in_sizes, int n_in,
                              void* d_out, int out_size, void* d_ws, size_t ws_size,
                              hipStream_t stream) {
  const int* doc_ids = (const int*)d_in[0];
  const int* pass_ids = (const int*)d_in[1];
  const int* edge_index = (const int*)d_in[2];
  const int* etype = (const int*)d_in[3];
  const float* embed = (const float*)d_in[4];
  const float* w_root1 = (const float*)d_in[5];
  const float* w_rel1 = (const float*)d_in[6];
  const float* b1 = (const float*)d_in[7];
  const float* w_root2 = (const float*)d_in[8];
  const float* w_rel2 = (const float*)d_in[9];
  const float* b2 = (const float*)d_in[10];
  const float* clf_w = (const float*)d_in[11];
  const float* clf_b = (const float*)d_in[12];
  float* out = (float*)d_out;

  const int* src = edge_index;
  const int* dst = edge_index + NEDGES;

  float* uf = (float*)d_ws;                    // (3*DIM+1)*4
  float* Tqf = uf + (3 * DIM + 1) * 4;         // NNODES*16
  float* v = Tqf + (size_t)NNODES * 16;        // 3*DIM+1
  int* deg = (int*)(v + 3 * DIM + 1);          // NBINS   (clear region start)
  int* bars = deg + NBINS;                     // 3*BAR_STRIDE
  int* bucket = bars + 3 * BAR_STRIDE;         // NBINS*CAP

  init_kernel<<<(CLRINTS + 255) / 256, 256, 0, stream>>>(deg);
  mega_kernel<<<NBLK, 256, 0, stream>>>(doc_ids, pass_ids, src, dst, etype,
                                        embed, w_root1, w_rel1, b1, w_root2,
                                        w_rel2, b2, clf_w, clf_b, uf, Tqf, v,
                                        deg, bars, bucket, out);
}

// Round 18
// 49.665 us; speedup vs baseline: 1.0062x; 1.0062x over previous
//
#include <hip/hip_runtime.h>

#define NDOCS 64
#define NPASS 1024
#define TITLE_LEN 128
#define SEQ 256
#define NEDGES 32768
#define NNODES 2112   // NDOCS + 2*NPASS
#define DIM 768
#define SPAN_TOK 30522
#define NREL 2
#define NBINS (NREL * NNODES)   // 4224
#define SPAN0 (NNODES - NPASS)  // 1088
#define CAP 48                  // max in-edges per bin; P(overflow)~1e-26
#define NBLK 1024               // 4 blocks/CU x 256 CUs, exactly co-resident
#define BAR_STRIDE 320
#define NSYNC 3
#define CLRINTS (NBINS + NSYNC * BAR_STRIDE)

typedef unsigned long long u64;

__device__ inline float wred(float s) {
#pragma unroll
  for (int off = 32; off > 0; off >>= 1) s += __shfl_down(s, off);
  return s;
}
__device__ inline float dot4(float4 a, float4 b) {
  return a.x * b.x + a.y * b.y + a.z * b.z + a.w * b.w;
}
// coherent (agent-scope relaxed) accessors: bypass non-coherent L1/L2
__device__ inline float cload(const float* p) {
  return __hip_atomic_load(p, __ATOMIC_RELAXED, __HIP_MEMORY_SCOPE_AGENT);
}
__device__ inline void cstore(float* p, float x) {
  __hip_atomic_store(p, x, __ATOMIC_RELAXED, __HIP_MEMORY_SCOPE_AGENT);
}
__device__ inline int ciload(const int* p) {
  return __hip_atomic_load(p, __ATOMIC_RELAXED, __HIP_MEMORY_SCOPE_AGENT);
}
__device__ inline void cistore(int* p, int x) {
  __hip_atomic_store(p, x, __ATOMIC_RELAXED, __HIP_MEMORY_SCOPE_AGENT);
}
__device__ inline u64 c8load(const u64* p) {
  return __hip_atomic_load(p, __ATOMIC_RELAXED, __HIP_MEMORY_SCOPE_AGENT);
}

// fully-relaxed grid barrier (no cache-maintenance ops). Store completion is
// guaranteed by __syncthreads()'s vmcnt(0) drain; cross-stage data moves via
// coherent accessors only. 16-group arrival tree avoids same-line contention.
__device__ inline void gbar(int* bars, int i) {
  __syncthreads();
  if (threadIdx.x == 0) {
    int* base = bars + i * BAR_STRIDE;
    int g = blockIdx.x >> 6;  // 16 groups of 64 blocks
    if (__hip_atomic_fetch_add(base + g * 16, 1, __ATOMIC_RELAXED,
                               __HIP_MEMORY_SCOPE_AGENT) == 63) {
      if (__hip_atomic_fetch_add(base + 256, 1, __ATOMIC_RELAXED,
                                 __HIP_MEMORY_SCOPE_AGENT) == 15) {
        __hip_atomic_store(base + 260, 1, __ATOMIC_RELAXED,
                           __HIP_MEMORY_SCOPE_AGENT);
      }
    }
    while (__hip_atomic_load(base + 260, __ATOMIC_RELAXED,
                             __HIP_MEMORY_SCOPE_AGENT) == 0)
      __builtin_amdgcn_s_sleep(1);
  }
  __syncthreads();
}

__global__ __launch_bounds__(256) void init_kernel(int* __restrict__ clr) {
  int i = blockIdx.x * 256 + threadIdx.x;
  if (i < CLRINTS) clr[i] = 0;
}

__global__ __launch_bounds__(256, 4) void mega_kernel(
    const int* __restrict__ doc_ids, const int* __restrict__ pass_ids,
    const int* __restrict__ src, const int* __restrict__ dst,
    const int* __restrict__ et, const float* __restrict__ embed,
    const float* __restrict__ w_root1, const float* __restrict__ w_rel1,
    const float* __restrict__ b1, const float* __restrict__ w_root2,
    const float* __restrict__ w_rel2, const float* __restrict__ b2,
    const float* __restrict__ clf_w, const float* __restrict__ clf_b,
    float* __restrict__ uf /* (3*DIM+1)*4 */, float* __restrict__ Tqf,
    float* __restrict__ v /* 3*DIM+1 */, int* __restrict__ deg,
    int* __restrict__ bars, int* __restrict__ bucket, float* __restrict__ out) {
  __shared__ __align__(16) float lds[(3 * DIM + 1) * 4];  // 36880 B
  __shared__ float red[4];
  const int tid = threadIdx.x;
  const int lane = tid & 63;
  const int wid = tid >> 6;
  const int b = blockIdx.x;

  // ======== stage A: scatter [0,128) | foldv [128,1024) ========
  if (b < 128) {
    int e = b * 256 + tid;
    int bin = et[e] * NNODES + dst[e];
    int slot = atomicAdd(&deg[bin], 1);  // device-scope: coherent
    if (slot < CAP) cistore(&bucket[bin * CAP + slot], src[e]);
  } else {
    int k = (b - 128) * 4 + wid;  // 3584 waves cover 2305 rows
    if (k <= 3 * DIM) {
      const float* row = (k < DIM) ? w_root2 + (size_t)k * DIM
                       : (k < 3 * DIM) ? w_rel2 + (size_t)(k - DIM) * DIM
                                       : b2;
      const float4* r4 = (const float4*)row;
      const float4* w4 = (const float4*)clf_w;
      float s = dot4(r4[lane], w4[lane]) + dot4(r4[lane + 64], w4[lane + 64]) +
                dot4(r4[lane + 128], w4[lane + 128]);
      s = wred(s);
      if (lane == 0) cstore(&v[k], s + (k == 3 * DIM ? clf_b[0] : 0.f));
    }
  }
  gbar(bars, 0);

  // ======== stage B: foldu, blocks [0,577) (rows k = b*4+wid) ========
  if (b <= 576) {
    const u64* v8 = (const u64*)v;
    for (int i = tid; i < 1152; i += 256) ((u64*)lds)[i] = c8load(&v8[i]);
    __syncthreads();
    int k = b * 4 + wid;
    if (k <= 3 * DIM) {
      const float* row = (k < DIM) ? w_root1 + (size_t)k * DIM
                       : (k < 3 * DIM) ? w_rel1 + (size_t)(k - DIM) * DIM
                                       : b1;
      const float4* r4 = (const float4*)row;
      const float4* v0 = (const float4*)lds;
      const float4* v1 = (const float4*)(lds + DIM);
      const float4* v2 = (const float4*)(lds + 2 * DIM);
      float s0 = 0.f, s1 = 0.f, s2 = 0.f;
#pragma unroll
      for (int i = 0; i < 3; ++i) {
        int j = lane + i * 64;
        float4 r = r4[j];
        s0 += dot4(r, v0[j]);
        s1 += dot4(r, v1[j]);
        s2 += dot4(r, v2[j]);
      }
      s0 = wred(s0); s1 = wred(s1); s2 = wred(s2);
      if (lane == 0) {
        cstore(&uf[k * 4 + 0], s0);
        cstore(&uf[k * 4 + 1], s1);
        cstore(&uf[k * 4 + 2], s2);
      }
    }
  }
  gbar(bars, 1);

  // ======== stage C: T[m][a][j] = x0[m].U_a[:,j], blocks [0,528) ========
  if (b < 528) {
    const u64* u8 = (const u64*)uf;
    for (int i = tid; i < 4610; i += 256) ((u64*)lds)[i] = c8load(&u8[i]);
    __syncthreads();
    int m = b * 4 + wid;  // 528*4 == 2112 exactly
    int tok = (m < NDOCS) ? doc_ids[m * TITLE_LEN]
            : (m < NDOCS + NPASS) ? pass_ids[(m - NDOCS) * SEQ]
                                  : SPAN_TOK;
    const float4* e4 = (const float4*)(embed + (size_t)tok * DIM);
    float s[9] = {};
#pragma unroll
    for (int i = 0; i < 3; ++i) {
      int j = lane + i * 64;
      float4 ev = e4[j];
#pragma unroll
      for (int q = 0; q < 4; ++q) {
        int k = j * 4 + q;
        float e1 = (q == 0) ? ev.x : (q == 1) ? ev.y : (q == 2) ? ev.z : ev.w;
#pragma unroll
        for (int a = 0; a < 3; ++a) {
          int base = (a * DIM + k) * 4;
          s[a * 3 + 0] += e1 * lds[base + 0];
          s[a * 3 + 1] += e1 * lds[base + 1];
          s[a * 3 + 2] += e1 * lds[base + 2];
        }
      }
    }
#pragma unroll
    for (int a = 0; a < 9; ++a) s[a] = wred(s[a]);
    if (lane == 0) {
#pragma unroll
      for (int a = 0; a < 3; ++a)
#pragma unroll
        for (int j = 0; j < 3; ++j)
          cstore(&Tqf[m * 16 + a * 4 + j], s[a * 3 + j]);
    }
  }
  gbar(bars, 2);

  // ======== stage D: final, one block per span node ========
  {
    int i = b;  // span idx 0..1023
    int n = SPAN0 + i;
    float Dj[3];
#pragma unroll
    for (int j = 0; j < 3; ++j) Dj[j] = cload(&uf[3 * DIM * 4 + j]);
    int c0n = ciload(&deg[n]), c1n = ciload(&deg[NNODES + n]);
    float i0n = 1.f / fmaxf((float)c0n, 1.f);
    float i1n = 1.f / fmaxf((float)c1n, 1.f);
    int tot = c0n + c1n;
    int q = tid & 7;  // 8 lanes per outer edge
    float zpart = 0.f;
    for (int o = tid >> 3; o < tot; o += 32) {
      int r = (o < c0n) ? 0 : 1;
      int oo = (o < c0n) ? o : o - c0n;
      int s = ciload(&bucket[(r * NNODES + n) * CAP + oo]);
      int j = 1 + r;
      float contrib = 0.f;
      if (q == 0)
        contrib = cload(&Tqf[s * 16 + j * 4 + 0])  // T[s][1+r][0]
                + cload(&Tqf[s * 16 + j])          // T[s][0][1+r]
                + Dj[j];
#pragma unroll
      for (int rp = 0; rp < 2; ++rp) {
        int cs = ciload(&deg[rp * NNODES + s]);
        float ssum = 0.f;
        for (int e = q; e < cs; e += 8) {
          int sp = ciload(&bucket[(rp * NNODES + s) * CAP + e]);
          ssum += cload(&Tqf[sp * 16 + (1 + rp) * 4 + j]);
        }
        contrib += ssum / fmaxf((float)cs, 1.f);
      }
      zpart += ((r == 0) ? i0n : i1n) * contrib;
    }
    zpart = wred(zpart);
    if (lane == 0) red[wid] = zpart;
    __syncthreads();
    if (tid == 0) {
      float z = cload(&Tqf[n * 16 + 0]) + Dj[0] + cload(&v[3 * DIM]) +
                red[0] + red[1] + red[2] + red[3];
      float sc = 1.f / (1.f + expf(-z));
      out[i] = expf(sc * 5.f);  // exp(score / TAU), TAU = 0.2
    }
  }
}

extern "C" void kernel_launch(void* const* d_in, const int* in_sizes, int n_in,
                              void* d_out, int out_size, void* d_ws, size_t ws_size,
                              hipStream_t stream) {
  const int* doc_ids = (const int*)d_in[0];
  const int* pass_ids = (const int*)d_in[1];
  const int* edge_index = (const int*)d_in[2];
  const int* etype = (const int*)d_in[3];
  const float* embed = (const float*)d_in[4];
  const float* w_root1 = (const float*)d_in[5];
  const float* w_rel1 = (const float*)d_in[6];
  const float* b1 = (const float*)d_in[7];
  const float* w_root2 = (const float*)d_in[8];
  const float* w_rel2 = (const float*)d_in[9];
  const float* b2 = (const float*)d_in[10];
  const float* clf_w = (const float*)d_in[11];
  const float* clf_b = (const float*)d_in[12];
  float* out = (float*)d_out;

  const int* src = edge_index;
  const int* dst = edge_index + NEDGES;

  float* uf = (float*)d_ws;                    // (3*DIM+1)*4
  float* Tqf = uf + (3 * DIM + 1) * 4;         // NNODES*16
  float* v = Tqf + (size_t)NNODES * 16;        // 3*DIM+1
  int* deg = (int*)(v + 3 * DIM + 1);          // NBINS (clear region start)
  int* bars = deg + NBINS;                     // NSYNC*BAR_STRIDE
  int* bucket = bars + NSYNC * BAR_STRIDE;     // NBINS*CAP

  init_kernel<<<(CLRINTS + 255) / 256, 256, 0, stream>>>(deg);
  mega_kernel<<<NBLK, 256, 0, stream>>>(doc_ids, pass_ids, src, dst, etype,
                                        embed, w_root1, w_rel1, b1, w_root2,
                                        w_rel2, b2, clf_w, clf_b, uf, Tqf, v,
                                        deg, bars, bucket, out);
}

// Round 19
// 30.083 us; speedup vs baseline: 1.6613x; 1.6510x over previous
//
#include <hip/hip_runtime.h>

#define NDOCS 64
#define NPASS 1024
#define TITLE_LEN 128
#define SEQ 256
#define NEDGES 32768
#define NNODES 2112   // NDOCS + 2*NPASS
#define DIM 768
#define SPAN_TOK 30522
#define NREL 2
#define NBINS (NREL * NNODES)   // 4224
#define SPAN0 (NNODES - NPASS)  // 1088
#define CAP 48                  // max in-edges per (rel,node) bin; P(overflow)~1e-26
#define NROWS (3 * DIM + 1)     // 2305 fold rows (incl. bias row)
#define SCATB 171               // ceil(NEDGES/192)

__device__ inline float wred(float s) {
#pragma unroll
  for (int off = 32; off > 0; off >>= 1) s += __shfl_down(s, off);
  return s;
}
__device__ inline float dot4(float4 a, float4 b) {
  return a.x * b.x + a.y * b.y + a.z * b.z + a.w * b.w;
}

// ---------- K1: foldv, one row per 192-thr block (2305) | clear deg (22) ----
// v[k] = row_k(Wcat2) . clf_w ; v[2304] = b2.clf_w + clf_b
__global__ __launch_bounds__(192) void foldv_clear_kernel(
    const float* __restrict__ w_root2, const float* __restrict__ w_rel2,
    const float* __restrict__ b2, const float* __restrict__ clf_w,
    const float* __restrict__ clf_b, float* __restrict__ v,
    int* __restrict__ deg) {
  __shared__ float sred[3];
  int b = blockIdx.x;
  int t = threadIdx.x;
  if (b < NROWS) {
    int k = b;
    const float* row = (k < DIM) ? w_root2 + (size_t)k * DIM
                     : (k < 3 * DIM) ? w_rel2 + (size_t)(k - DIM) * DIM
                                     : b2;
    float s = dot4(((const float4*)row)[t], ((const float4*)clf_w)[t]);
    s = wred(s);
    int lane = t & 63, wv = t >> 6;
    if (lane == 0) sred[wv] = s;
    __syncthreads();
    if (t == 0)
      v[k] = sred[0] + sred[1] + sred[2] + (k == 3 * DIM ? clf_b[0] : 0.f);
  } else {
    int i = (b - NROWS) * 192 + t;
    if (i < NBINS) deg[i] = 0;
  }
}

// ---------- K2: bucket-scatter (171, guarded) | foldu row/block (2305) ------
// bucket[bin*CAP + slot] = src, deg[bin] = count  (hist+scatter in one pass)
// U4[k] = {row_k(Wcat1).v0, .v1, .v2}; U4[2304] = d (bias fold)
__global__ __launch_bounds__(192) void bucket_foldu_kernel(
    const int* __restrict__ srcv, const int* __restrict__ dst,
    const int* __restrict__ et, int* __restrict__ deg, int* __restrict__ bucket,
    const float* __restrict__ w_root1, const float* __restrict__ w_rel1,
    const float* __restrict__ b1, const float* __restrict__ v,
    float4* __restrict__ U4) {
  __shared__ float sred[3][3];
  int b = blockIdx.x;
  int t = threadIdx.x;
  if (b < SCATB) {
    int e = b * 192 + t;
    if (e < NEDGES) {
      int bin = et[e] * NNODES + dst[e];
      int slot = atomicAdd(&deg[bin], 1);
      if (slot < CAP) bucket[bin * CAP + slot] = srcv[e];
    }
  } else {
    int k = b - SCATB;
    const float* row = (k < DIM) ? w_root1 + (size_t)k * DIM
                     : (k < 3 * DIM) ? w_rel1 + (size_t)(k - DIM) * DIM
                                     : b1;
    float4 r = ((const float4*)row)[t];
    float s0 = dot4(r, ((const float4*)v)[t]);
    float s1 = dot4(r, ((const float4*)(v + DIM))[t]);
    float s2 = dot4(r, ((const float4*)(v + 2 * DIM))[t]);
    s0 = wred(s0); s1 = wred(s1); s2 = wred(s2);
    int lane = t & 63, wv = t >> 6;
    if (lane == 0) { sred[wv][0] = s0; sred[wv][1] = s1; sred[wv][2] = s2; }
    __syncthreads();
    if (t == 0)
      U4[k] = make_float4(sred[0][0] + sred[1][0] + sred[2][0],
                          sred[0][1] + sred[1][1] + sred[2][1],
                          sred[0][2] + sred[1][2] + sred[2][2], 0.f);
  }
}

// ---------- K3: T[m][a][j] = x0[m].U_a[:,j], one 256-thr block per node ------
// m in [0,1088]; m==1088 is the shared span prototype (token SPAN_TOK).
// Threads 0..191 each own one float4 (4 k's) of the 768-dim; 4-wave LDS reduce.
__global__ __launch_bounds__(256) void t_kernel(
    const int* __restrict__ doc_ids, const int* __restrict__ pass_ids,
    const float* __restrict__ embed, const float4* __restrict__ U4,
    float4* __restrict__ Tq) {
  __shared__ float sred[4][9];
  int m = blockIdx.x;  // 0..1088
  int t = threadIdx.x;
  int wv = t >> 6, lane = t & 63;
  int tok = (m < NDOCS) ? doc_ids[m * TITLE_LEN]
          : (m < NDOCS + NPASS) ? pass_ids[(m - NDOCS) * SEQ]
                                : SPAN_TOK;
  float s[9] = {};
  if (t < 192) {
    const float4* e4 = (const float4*)(embed + (size_t)tok * DIM);
    float4 ev = e4[t];
#pragma unroll
    for (int q = 0; q < 4; ++q) {
      int k = t * 4 + q;
      float e1 = (q == 0) ? ev.x : (q == 1) ? ev.y : (q == 2) ? ev.z : ev.w;
      float4 u0 = U4[k], u1 = U4[DIM + k], u2 = U4[2 * DIM + k];
      s[0] += e1 * u0.x; s[1] += e1 * u0.y; s[2] += e1 * u0.z;
      s[3] += e1 * u1.x; s[4] += e1 * u1.y; s[5] += e1 * u1.z;
      s[6] += e1 * u2.x; s[7] += e1 * u2.y; s[8] += e1 * u2.z;
    }
  }
#pragma unroll
  for (int a = 0; a < 9; ++a) s[a] = wred(s[a]);
  if (lane == 0) {
#pragma unroll
    for (int a = 0; a < 9; ++a) sred[wv][a] = s[a];
  }
  __syncthreads();
  if (t == 0) {
    float r[9];
#pragma unroll
    for (int a = 0; a < 9; ++a)
      r[a] = sred[0][a] + sred[1][a] + sred[2][a] + sred[3][a];
    Tq[m * 4 + 0] = make_float4(r[0], r[1], r[2], 0.f);
    Tq[m * 4 + 1] = make_float4(r[3], r[4], r[5], 0.f);
    Tq[m * 4 + 2] = make_float4(r[6], r[7], r[8], 0.f);
  }
}

// ---------- K4: final, flattened traversal; one 128-thr block per span node --
// z = T[n][0][0] + D[0] + c0 + sum_{own edges (s,r)} i_r(n) * (
//       T[s][1+r][0] + T[s][0][1+r] + D[1+r]
//     + sum_{rp} mean_{s' in bin(rp,s)} T[s'][1+rp][1+r] )
// 4 lanes per outer edge (o = t>>2, stride 32); q-lanes stride-4 over inner
// bins; division by max(cs,1) distributes the mean; 2-wave LDS reduce.
__global__ __launch_bounds__(128) void final_kernel(
    const float4* __restrict__ Tq, const int* __restrict__ deg,
    const int* __restrict__ bucket, const float4* __restrict__ U4,
    const float* __restrict__ v, float* __restrict__ out) {
  __shared__ float red2[2];
  int i = blockIdx.x;  // span idx 0..1023
  int t = threadIdx.x;
  int lane = t & 63, wv = t >> 6;
  int n = SPAN0 + i;
  const float* Tqf = (const float*)Tq;
  float4 D = U4[3 * DIM];
  const float* Df = (const float*)&D;
  int c0n = deg[n], c1n = deg[NNODES + n];
  float i0n = 1.f / fmaxf((float)c0n, 1.f);
  float i1n = 1.f / fmaxf((float)c1n, 1.f);
  int tot = c0n + c1n;
  int q = t & 3;
  float zpart = 0.f;
  for (int o = t >> 2; o < tot; o += 32) {
    int r = (o < c0n) ? 0 : 1;
    int oo = (o < c0n) ? o : o - c0n;
    int s = bucket[(r * NNODES + n) * CAP + oo];
    int j = 1 + r;
    int ts = (s < SPAN0) ? s : SPAN0;
    float contrib = 0.f;
    if (q == 0)
      contrib = Tqf[ts * 16 + j * 4 + 0]  // T[s][1+r][0]
              + Tqf[ts * 16 + j]          // T[s][0][1+r]
              + Df[j];
#pragma unroll
    for (int rp = 0; rp < 2; ++rp) {
      int cs = deg[rp * NNODES + s];
      float ssum = 0.f;
      for (int e = q; e < cs; e += 4) {
        int sp = bucket[(rp * NNODES + s) * CAP + e];
        int tsp = (sp < SPAN0) ? sp : SPAN0;
        ssum += Tqf[tsp * 16 + (1 + rp) * 4 + j];
      }
      contrib += ssum / fmaxf((float)cs, 1.f);
    }
    zpart += ((r == 0) ? i0n : i1n) * contrib;
  }
  zpart = wred(zpart);
  if (lane == 0) red2[wv] = zpart;
  __syncthreads();
  if (t == 0) {
    float z = Tqf[SPAN0 * 16 + 0] + Df[0] + v[3 * DIM] + red2[0] + red2[1];
    float sc = 1.f / (1.f + expf(-z));
    out[i] = expf(sc * 5.f);  // exp(score / TAU), TAU = 0.2
  }
}

extern "C" void kernel_launch(void* const* d_in, const int* in_sizes, int n_in,
                              void* d_out, int out_size, void* d_ws, size_t ws_size,
                              hipStream_t stream) {
  const int* doc_ids = (const int*)d_in[0];
  const int* pass_ids = (const int*)d_in[1];
  const int* edge_index = (const int*)d_in[2];
  const int* etype = (const int*)d_in[3];
  const float* embed = (const float*)d_in[4];
  const float* w_root1 = (const float*)d_in[5];
  const float* w_rel1 = (const float*)d_in[6];
  const float* b1 = (const float*)d_in[7];
  const float* w_root2 = (const float*)d_in[8];
  const float* w_rel2 = (const float*)d_in[9];
  const float* b2 = (const float*)d_in[10];
  const float* clf_w = (const float*)d_in[11];
  const float* clf_b = (const float*)d_in[12];
  float* out = (float*)d_out;

  const int* src = edge_index;
  const int* dst = edge_index + NEDGES;

  float4* U4 = (float4*)d_ws;                      // 2305 float4
  float4* Tq = U4 + NROWS;                         // 1089*4 float4
  float* v = (float*)(Tq + (size_t)(SPAN0 + 1) * 4);  // 2305 floats
  int* deg = (int*)(v + NROWS);                    // NBINS
  int* bucket = deg + NBINS;                       // NBINS * CAP

  foldv_clear_kernel<<<NROWS + 22, 192, 0, stream>>>(w_root2, w_rel2, b2, clf_w,
                                                     clf_b, v, deg);
  bucket_foldu_kernel<<<SCATB + NROWS, 192, 0, stream>>>(src, dst, etype, deg,
                                                         bucket, w_root1,
                                                         w_rel1, b1, v, U4);
  t_kernel<<<SPAN0 + 1, 256, 0, stream>>>(doc_ids, pass_ids, embed, U4, Tq);
  final_kernel<<<NPASS, 128, 0, stream>>>(Tq, deg, bucket, U4, v, out);
}